// Round 2
// 180.544 us; speedup vs baseline: 1.2070x; 1.2070x over previous
//
#include <hip/hip_runtime.h>
#include <cstdint>
#include <cstddef>

#define SEQ   2048
#define EDIM  256
#define NBATCH 16
#define XLD   264   // xt row pitch (u16): +8 pad rotates banks by 4 dwords/row

typedef unsigned short u16;
typedef __attribute__((ext_vector_type(8))) __bf16 bf16x8;
typedef __attribute__((ext_vector_type(4))) float f32x4;

__device__ __forceinline__ float bf2f(u16 u) {
  union { unsigned int w; float f; } v; v.w = ((unsigned int)u) << 16; return v.f;
}
__device__ __forceinline__ u16 f2bf(float f) {
  union { float f; unsigned int w; } v; v.f = f;
  unsigned int r = v.w + 0x7fffu + ((v.w >> 16) & 1u);
  return (u16)(r >> 16);
}
// packed f32->bf16 pair (RNE), lo in bits[15:0]
__device__ __forceinline__ unsigned int pk2(float lo, float hi) {
  unsigned int d;
  asm("v_cvt_pk_bf16_f32 %0, %1, %2" : "=v"(d) : "v"(lo), "v"(hi));
  return d;
}
__device__ __forceinline__ float fast_cos(float x) {
  float r = x * 0.15915494309189535f;
  r = r - floorf(r);
  return __builtin_amdgcn_cosf(r);
}
__device__ __forceinline__ void unpack8(bf16x8 v, float* o) {
  const u16* p = (const u16*)&v;
  #pragma unroll
  for (int j = 0; j < 8; ++j) o[j] = bf2f(p[j]);
}

// -------- sniff: float inputs f32 (flag=1) or bf16 (flag=0) --------
__global__ void sniff_kernel(const void* embed, int* flag) {
  int t = threadIdx.x;
  const u16* p = (const u16*)embed;
  int c = 0;
  #pragma unroll
  for (int j = 0; j < 8; ++j) {
    u16 v = p[t * 8 + j];
    int e = (v >> 7) & 0xff;
    c += (e > 128) ? 1 : 0;
  }
  #pragma unroll
  for (int d = 1; d < 64; d <<= 1) c += __shfl_xor(c, d);
  if (t == 0) *flag = (c > 64) ? 1 : 0;
}

// -------- canonicalize SMALL float params to bf16 in ws; also PE freq table --------
// layout (elems): 0 attn_theta(128) | 128 combine_b(512) | 640 ffn_theta(16) |
// 656 lin1_b(1024) | 1680 lin2_b(512) | 2192 ln1_g(512) | 2704 ln1_b(512) |
// 3216 ln2_g(512) | 3728 ln2_b(512) | 4240 cls_w(512) | 4752 cls_b(2) | 4754 end
struct CanonArgs { const void* p[11]; };

__global__ void canon_kernel(CanonArgs a, const int* __restrict__ flag,
                             u16* __restrict__ dst, float* __restrict__ divt) {
  const int off[12] = {0, 128, 640, 656, 1680, 2192, 2704, 3216, 3728, 4240, 4752, 4754};
  int i = blockIdx.x * 256 + threadIdx.x;
  if (i < 128) {
    const float c0 = 9.210340371976184f / 128.f;   // ln(10000)/128
    const float inv2pi = 0.15915494309189535f;
    divt[i] = __expf(-(float)i * c0) * inv2pi;
  }
  if (i >= 4754) return;
  int isf32 = *flag;
  int s = 0;
  #pragma unroll
  for (int k = 0; k < 10; ++k) s += (i >= off[k + 1]) ? 1 : 0;
  int j = i - off[s];
  dst[i] = isf32 ? f2bf(((const float*)a.p[s])[j]) : ((const u16*)a.p[s])[j];
}

// ---- prep: big weights -> staging layouts (reads ORIGINAL inputs) ----
// cwT/l2T: [K/8][256][8] (k-chunked, n-major, k-inner); w1T: [L][512 ffn][8 q]
__global__ void prep_kernel(const void* __restrict__ cw, const void* __restrict__ w1,
                            const void* __restrict__ l2, const int* __restrict__ flag,
                            u16* __restrict__ cwT, u16* __restrict__ l2T,
                            u16* __restrict__ w1T) {
  int id = blockIdx.x * 256 + threadIdx.x;
  int isf32 = *flag;
  if (id < 131072) {
    int l = id >> 16, rem = id & 65535;
    int kc = rem >> 11, n = (rem >> 3) & 255, kj = rem & 7;
    int idx = l * 65536 + (kc * 8 + kj) * 256 + n;
    cwT[id] = isf32 ? f2bf(((const float*)cw)[idx]) : ((const u16*)cw)[idx];
  } else if (id < 131072 + 262144) {
    int j = id - 131072;
    int l = j >> 17, rem = j & 131071;
    int kc = rem >> 11, n = (rem >> 3) & 255, kj = rem & 7;
    int idx = l * 131072 + (kc * 8 + kj) * 256 + n;
    l2T[j] = isf32 ? f2bf(((const float*)l2)[idx]) : ((const u16*)l2)[idx];
  } else {
    int j = id - (131072 + 262144);
    if (j < 2 * 512 * 8) {
      int l = j >> 12, rem = j & 4095;
      int c = rem >> 3, jj = rem & 7;             // w1T[l][c][jj] = w1[l][jj][c]
      int idx = l * 4096 + jj * 512 + c;
      w1T[j] = isf32 ? f2bf(((const float*)w1)[idx]) : ((const u16*)w1)[idx];
    }
  }
}

// ====== MEGA: embed+PE -> [attn GEMM+LN1 -> q -> h(MFMA) -> ffn GEMM+LN2] x2 -> pool ======
__launch_bounds__(256, 2)
__global__ void mega_kernel(const int* __restrict__ tokens, const void* __restrict__ embed,
                            const int* __restrict__ flag, const u16* __restrict__ canon,
                            const u16* __restrict__ cwT, const u16* __restrict__ l2T,
                            const u16* __restrict__ w1T, const float* __restrict__ divt,
                            float* __restrict__ pooled) {
  __shared__ u16 xt[64 * XLD];          // 33792 B persistent x tile
  __shared__ union {
    struct { u16 Bt[256 * 64]; u16 At[64 * 64]; u16 qs[64 * 8]; } k;  // 41984 B
    struct { float2 sstat[64][5]; float2 sms[64]; } ln;               // 3072 B
  } sh;
  __shared__ u16 thL[64];               // 128 B

  const int tid = threadIdx.x;
  const int wave = tid >> 6, lane = tid & 63;
  const int fr = lane & 15, fq = lane >> 4;
  const int m0 = blockIdx.x * 64;
  const int isf32 = *flag;

  int cols[4];
  #pragma unroll
  for (int ni = 0; ni < 4; ++ni) cols[ni] = wave * 64 + ni * 16 + fr;

  // ---------- embed + positional encoding -> xt ----------
  {
    #pragma unroll
    for (int it = 0; it < 8; ++it) {
      int c = it * 256 + tid;
      int r = c >> 5, e8 = c & 31;       // 64 rows x 32 8-elem chunks
      int tok = tokens[m0 + r];
      float ev[8];
      if (isf32) {
        const float* ep = (const float*)embed + (size_t)tok * EDIM + e8 * 8;
        float4 a = *(const float4*)ep, b = *(const float4*)(ep + 4);
        ev[0]=a.x; ev[1]=a.y; ev[2]=a.z; ev[3]=a.w; ev[4]=b.x; ev[5]=b.y; ev[6]=b.z; ev[7]=b.w;
      } else {
        const u16* ep = (const u16*)embed + (size_t)tok * EDIM + e8 * 8;
        uint4 v = *(const uint4*)ep;
        unpack8(*(const bf16x8*)&v, ev);
      }
      float sf = (float)((m0 + r) & (SEQ - 1));
      float4 dv = *(const float4*)(divt + e8 * 4);
      float r0 = sf * dv.x; r0 -= floorf(r0);
      float r1 = sf * dv.y; r1 -= floorf(r1);
      float r2 = sf * dv.z; r2 -= floorf(r2);
      float r3 = sf * dv.w; r3 -= floorf(r3);
      uint4 o;
      o.x = pk2(ev[0] + __builtin_amdgcn_sinf(r0), ev[1] + __builtin_amdgcn_cosf(r0));
      o.y = pk2(ev[2] + __builtin_amdgcn_sinf(r1), ev[3] + __builtin_amdgcn_cosf(r1));
      o.z = pk2(ev[4] + __builtin_amdgcn_sinf(r2), ev[5] + __builtin_amdgcn_cosf(r2));
      o.w = pk2(ev[6] + __builtin_amdgcn_sinf(r3), ev[7] + __builtin_amdgcn_cosf(r3));
      *(uint4*)(xt + r * XLD + e8 * 8) = o;
    }
  }
  __syncthreads();

  f32x4 acc[4][4];

  auto mfma_step = [&]() {
    const bf16x8* Av = (const bf16x8*)sh.k.At;
    const bf16x8* Bv = (const bf16x8*)sh.k.Bt;
    #pragma unroll
    for (int ks = 0; ks < 2; ++ks) {
      const int kc = ks * 4 + fq;
      bf16x8 af[4], bfv[4];
      #pragma unroll
      for (int mi = 0; mi < 4; ++mi) af[mi] = Av[kc * 64 + ((mi * 16 + fr) ^ kc)];
      #pragma unroll
      for (int ni = 0; ni < 4; ++ni) bfv[ni] = Bv[kc * 256 + cols[ni]];
      #pragma unroll
      for (int mi = 0; mi < 4; ++mi)
        #pragma unroll
        for (int ni = 0; ni < 4; ++ni)
          acc[mi][ni] = __builtin_amdgcn_mfma_f32_16x16x32_bf16(af[mi], bfv[ni], acc[mi][ni], 0, 0, 0);
    }
  };

  // GEMM bias folded into acc init (C/D: row=mi*16+fq*4+rg, col=cols[ni])
  auto acc_init = [&](const u16* bias) {
    #pragma unroll
    for (int ni = 0; ni < 4; ++ni) {
      float b = bf2f(bias[cols[ni]]);
      #pragma unroll
      for (int mi = 0; mi < 4; ++mi) acc[mi][ni] = {b, b, b, b};
    }
  };

  // residual + LN over acc; xt updated in place
  auto epilogue = [&](const u16* gamma, const u16* beta) {
    #pragma unroll
    for (int mi = 0; mi < 4; ++mi)
      #pragma unroll
      for (int rg = 0; rg < 4; ++rg) {
        int lrow = mi * 16 + fq * 4 + rg;
        #pragma unroll
        for (int ni = 0; ni < 4; ++ni)
          acc[mi][ni][rg] += bf2f(xt[lrow * XLD + cols[ni]]);
      }
    float sr[4][4], sq[4][4];
    #pragma unroll
    for (int mi = 0; mi < 4; ++mi)
      #pragma unroll
      for (int rg = 0; rg < 4; ++rg) {
        float a = 0.f, b = 0.f;
        #pragma unroll
        for (int ni = 0; ni < 4; ++ni) { float t2 = acc[mi][ni][rg]; a += t2; b += t2 * t2; }
        sr[mi][rg] = a; sq[mi][rg] = b;
      }
    #pragma unroll
    for (int d = 1; d < 16; d <<= 1)
      #pragma unroll
      for (int mi = 0; mi < 4; ++mi)
        #pragma unroll
        for (int rg = 0; rg < 4; ++rg) {
          sr[mi][rg] += __shfl_xor(sr[mi][rg], d);
          sq[mi][rg] += __shfl_xor(sq[mi][rg], d);
        }
    if (fr == 0) {
      #pragma unroll
      for (int mi = 0; mi < 4; ++mi)
        #pragma unroll
        for (int rg = 0; rg < 4; ++rg)
          sh.ln.sstat[mi * 16 + fq * 4 + rg][wave] = float2{sr[mi][rg], sq[mi][rg]};
    }
    __syncthreads();
    if (tid < 64) {
      float s = 0.f, s2 = 0.f;
      #pragma unroll
      for (int w = 0; w < 4; ++w) { float2 p = sh.ln.sstat[tid][w]; s += p.x; s2 += p.y; }
      float mean = s * (1.f / 256.f);
      float var = fmaxf(s2 * (1.f / 256.f) - mean * mean, 0.f);
      sh.ln.sms[tid] = float2{mean, rsqrtf(var + 1e-5f)};
    }
    __syncthreads();
    float gcol[4], btc[4];
    #pragma unroll
    for (int ni = 0; ni < 4; ++ni) { gcol[ni] = bf2f(gamma[cols[ni]]); btc[ni] = bf2f(beta[cols[ni]]); }
    #pragma unroll
    for (int mi = 0; mi < 4; ++mi)
      #pragma unroll
      for (int rg = 0; rg < 4; ++rg) {
        int lrow = mi * 16 + fq * 4 + rg;
        float2 ms = sh.ln.sms[lrow];
        #pragma unroll
        for (int ni = 0; ni < 4; ++ni) {
          float o = (acc[mi][ni][rg] - ms.x) * ms.y * gcol[ni] + btc[ni];
          xt[lrow * XLD + cols[ni]] = f2bf(o);
        }
      }
    __syncthreads();
  };

  for (int l = 0; l < 2; ++l) {
    // ---------- attn: acc = cos(xt + theta) @ cwT + combine_b ----------
    if (tid < 8) ((uint4*)thL)[tid] = ((const uint4*)(canon + l * 64))[tid];
    __syncthreads();
    acc_init(canon + 128 + l * 256);
    {
      const u16* Bbase = cwT + l * 65536;
      for (int k0 = 0; k0 < 256; k0 += 64) {
        const u16* bsrc = Bbase + (k0 >> 3) * 2048;
        #pragma unroll
        for (int it = 0; it < 8; ++it) {
          int c = tid + it * 256;
          __builtin_amdgcn_global_load_lds(
              (const __attribute__((address_space(1))) void*)(bsrc + (size_t)c * 8),
              (__attribute__((address_space(3))) void*)(sh.k.Bt + c * 8), 16, 0, 0);
        }
        #pragma unroll
        for (int it = 0; it < 2; ++it) {
          int c = it * 256 + tid;
          int f8 = c >> 6, r = c & 63;       // f8 wave-uniform
          uint4 g = *(const uint4*)(xt + r * XLD + k0 + f8 * 8);
          const u16* gp = (const u16*)&g;
          float cv[8];
          #pragma unroll
          for (int j = 0; j < 8; ++j)
            cv[j] = fast_cos(bf2f(gp[j]) + bf2f(thL[f8 * 8 + j]));
          uint4 o;
          o.x = pk2(cv[0], cv[1]); o.y = pk2(cv[2], cv[3]);
          o.z = pk2(cv[4], cv[5]); o.w = pk2(cv[6], cv[7]);
          ((uint4*)sh.k.At)[f8 * 64 + (r ^ f8)] = o;
        }
        __syncthreads();
        mfma_step();
        __syncthreads();
      }
    }
    epilogue(canon + 2192 + l * 256, canon + 2704 + l * 256);

    // ---------- ffn ----------
    const u16* B2 = l2T + (size_t)l * 131072;
    // early-issue Bt chunk 0 (hidden behind q-stage + preloads + barrier)
    #pragma unroll
    for (int it = 0; it < 8; ++it) {
      int c = tid + it * 256;
      __builtin_amdgcn_global_load_lds(
          (const __attribute__((address_space(1))) void*)(B2 + (size_t)c * 8),
          (__attribute__((address_space(3))) void*)(sh.k.Bt + c * 8), 16, 0, 0);
    }
    // q = cos(xt[:, :8]) * cos(ffn_theta)
    #pragma unroll
    for (int rep = 0; rep < 2; ++rep) {
      int idx = tid + rep * 256;
      int r = idx >> 3, n = idx & 7;
      float cth = fast_cos(bf2f(canon[640 + l * 8 + n]));
      sh.k.qs[r * 8 + n] = f2bf(fast_cos(bf2f(xt[r * XLD + n])) * cth);
    }
    // preload W1^T fragments (A-side of h^T MFMA) + bias pairs; zero lanes fq>0 (K pad)
    bf16x8 aW1[8]; uint2 b1p[8];
    #pragma unroll
    for (int c = 0; c < 8; ++c) {
      uint4 t = {0u, 0u, 0u, 0u};
      if (fq == 0) t = *(const uint4*)(w1T + (size_t)l * 4096 + (size_t)(c * 64 + wave * 16 + fr) * 8);
      aW1[c] = *(const bf16x8*)&t;
      b1p[c] = *(const uint2*)(canon + 656 + l * 512 + c * 64 + wave * 16 + fq * 4);
    }
    __syncthreads();   // qs visible; all waves' chunk-0 Bt loads drained
    // preload q^T fragments (B-side), zero lanes fq>0
    bf16x8 bq[4];
    #pragma unroll
    for (int ni = 0; ni < 4; ++ni) {
      uint4 t = {0u, 0u, 0u, 0u};
      if (fq == 0) t = ((const uint4*)sh.k.qs)[ni * 16 + fr];
      bq[ni] = *(const bf16x8*)&t;
    }
    acc_init(canon + 1680 + l * 256);
    #pragma unroll
    for (int c8 = 0; c8 < 8; ++c8) {
      // ---- h^T via MFMA: D = W1^T-slice @ q^T + b1 (K=32, only k<8 nonzero) ----
      // lane(fr,fq) reg rg, frag ni: h_pre[ffn = c8*64+wave*16+fq*4+rg][seq = ni*16+fr]
      {
        float b0 = bf2f((u16)(b1p[c8].x & 0xffffu)), b1v = bf2f((u16)(b1p[c8].x >> 16));
        float b2 = bf2f((u16)(b1p[c8].y & 0xffffu)), b3 = bf2f((u16)(b1p[c8].y >> 16));
        const int kcL = wave * 2 + (fq >> 1);       // At k-chunk this lane writes
        const int halfoff = (fq & 1) * 4;
        #pragma unroll
        for (int ni = 0; ni < 4; ++ni) {
          f32x4 hacc;
          hacc[0] = b0; hacc[1] = b1v; hacc[2] = b2; hacc[3] = b3;
          hacc = __builtin_amdgcn_mfma_f32_16x16x32_bf16(aW1[c8], bq[ni], hacc, 0, 0, 0);
          float h0 = fmaxf(hacc[0], 0.f), h1 = fmaxf(hacc[1], 0.f);
          float h2 = fmaxf(hacc[2], 0.f), h3 = fmaxf(hacc[3], 0.f);
          uint2 dw; dw.x = pk2(h0, h1); dw.y = pk2(h2, h3);
          int r = ni * 16 + fr;
          *(uint2*)(sh.k.At + ((kcL * 64 + (r ^ kcL)) * 8 + halfoff)) = dw;
        }
      }
      __syncthreads();
      mfma_step();
      __syncthreads();
      if (c8 < 7) {
        const u16* bsrc = B2 + (size_t)(c8 + 1) * 16384;
        #pragma unroll
        for (int it = 0; it < 8; ++it) {
          int c = tid + it * 256;
          __builtin_amdgcn_global_load_lds(
              (const __attribute__((address_space(1))) void*)(bsrc + (size_t)c * 8),
              (__attribute__((address_space(3))) void*)(sh.k.Bt + c * 8), 16, 0, 0);
        }
      }
    }
    epilogue(canon + 3216 + l * 256, canon + 3728 + l * 256);
  }

  // ---------- pool: per-block column sums -> atomicAdd ----------
  {
    float s = 0.f;
    #pragma unroll 8
    for (int r = 0; r < 64; ++r) s += bf2f(xt[r * XLD + tid]);
    atomicAdd(&pooled[(m0 >> 11) * EDIM + tid], s);
  }
}

__global__ void logits_kernel(const float* __restrict__ pooled, const u16* __restrict__ clsw,
                              const u16* __restrict__ clsb, const int* __restrict__ flag,
                              void* __restrict__ out) {
  int t = threadIdx.x;
  int b = t >> 4, sub = t & 15;
  float a0 = 0.f, a1 = 0.f;
  #pragma unroll
  for (int j = 0; j < 16; ++j) {
    int e = sub * 16 + j;
    float p = pooled[b * 256 + e];
    a0 += p * bf2f(clsw[e * 2 + 0]);
    a1 += p * bf2f(clsw[e * 2 + 1]);
  }
  #pragma unroll
  for (int d = 1; d < 16; d <<= 1) {
    a0 += __shfl_xor(a0, d);
    a1 += __shfl_xor(a1, d);
  }
  if (sub == 0) {
    float o0 = a0 * (1.f / 2048.f) + bf2f(clsb[0]);
    float o1 = a1 * (1.f / 2048.f) + bf2f(clsb[1]);
    if (*flag) {
      ((float*)out)[b * 2 + 0] = o0; ((float*)out)[b * 2 + 1] = o1;
    } else {
      ((u16*)out)[b * 2 + 0] = f2bf(o0); ((u16*)out)[b * 2 + 1] = f2bf(o1);
    }
  }
}

extern "C" void kernel_launch(void* const* d_in, const int* in_sizes, int n_in,
                              void* d_out, int out_size, void* d_ws, size_t ws_size,
                              hipStream_t stream) {
  const int* tokens = (const int*)d_in[0];

  char* ws = (char*)d_ws;
  u16*   canon  = (u16*)(ws + 0);              //  9.3 KB canonical bf16 small params
  u16*   cwT    = (u16*)(ws + 16384);          //  256 KB
  u16*   l2T    = (u16*)(ws + 278528);         //  512 KB
  u16*   w1T    = (u16*)(ws + 802816);         //   16 KB
  float* pooled = (float*)(ws + 819200);       //   16 KB
  int*   flag   = (int*)(ws + 835584);         //    4 B
  float* divt   = (float*)(ws + 835600);       //  512 B PE freq table

  sniff_kernel<<<1, 64, 0, stream>>>(d_in[1], flag);

  CanonArgs ca;
  ca.p[0] = d_in[2];  ca.p[1] = d_in[4];  ca.p[2] = d_in[5];  ca.p[3] = d_in[7];
  ca.p[4] = d_in[9];  ca.p[5] = d_in[10]; ca.p[6] = d_in[11]; ca.p[7] = d_in[12];
  ca.p[8] = d_in[13]; ca.p[9] = d_in[14]; ca.p[10] = d_in[15];
  canon_kernel<<<19, 256, 0, stream>>>(ca, flag, canon, divt);

  prep_kernel<<<1568, 256, 0, stream>>>(d_in[3], d_in[6], d_in[8], flag, cwT, l2T, w1T);

  hipMemsetAsync(pooled, 0, NBATCH * EDIM * sizeof(float), stream);

  mega_kernel<<<512, 256, 0, stream>>>(tokens, d_in[1], flag, canon, cwT, l2T, w1T, divt, pooled);

  logits_kernel<<<1, 256, 0, stream>>>(pooled, canon + 4240, canon + 4752, flag, d_out);
}